// Round 7
// baseline (132.189 us; speedup 1.0000x reference)
//
#include <hip/hip_runtime.h>
#include <stdint.h>
#include <stddef.h>

// ---------------------------------------------------------------------------
// cseft reassociated (no [H,N,N] scores). 4 launches (R0 dataflow, R6 tile):
//   1. prep:  xb=bf16(x), yb=bf16(y), w1t=bf16(W1^T) [1024,512],
//             w23t=bf16([W2|W3]^T) [2048,512]
//   2. stage_b: kvt[2048,4096] = w23t @ yb^T   (512 tiles)
//               qb [4096,1024] = xb @ w1t^T    (256 tiles)
//   3. build_u: Ut[s*128+d][h*128+dp] = cw[h]*sc * V_s @ K_s^T (K=256)
//   4. gemm_out: out[4096,2048] = qb @ Ut^T  (K=1024, fp32 out)
// N=4096 K=512 H=8 Dh=128 nItem=256 nSet=16 hardcoded.
//
// Accounting model (R6 post-mortem): dur ≈ 90 (harness fill floor) + prep 8
// + gaps 5.5/launch-gap + GEMM ~10. R1's build_m split was a net LOSS
// (+gap +build_m to save FLOPs that were never the bottleneck) -> reverted.
// gemm_tile: BK=64 (128B cache-line staging), dbuf 2x32KB, 1 barrier/step,
// T2 both-sides XOR swizzle (rule #21: linear LDS dest + pre-swizzled global
// source + same XOR on ds_read), T1 bijective XCD swizzle on big grids.
//
// Fusion attempts FAILED twice (R3 coop: never ran under graph capture;
// R5 sw-barrier: replay-divergent race — fence insufficient for cross-XCD
// L2 or graph interplay). Kernel boundaries are the verified coherence
// points. Do not re-fuse without buffer_wbl2/buffer_inv + a probe round.
// ---------------------------------------------------------------------------

typedef short short8 __attribute__((ext_vector_type(8)));
typedef float f32x4 __attribute__((ext_vector_type(4)));

#define AS1 __attribute__((address_space(1)))
#define AS3 __attribute__((address_space(3)))

__device__ __forceinline__ void gl_lds16(const void* g, void* l) {
    __builtin_amdgcn_global_load_lds((AS1 void*)(uintptr_t)g, (AS3 void*)l, 16, 0, 0);
}

__device__ __forceinline__ short f2bf(float f) {
    union { float f; unsigned u; } v; v.f = f;
    unsigned r = v.u + 0x7FFFu + ((v.u >> 16) & 1u);
    return (short)(r >> 16);
}

// --- prep: 0..1023 x->xb, 1024..2047 y->yb, 2048..3071 W2/W3->w23t (T),
//     3072..3583 W1->w1t (T). 3584 blocks x 256 thr.
__global__ __launch_bounds__(256)
void prep(const float* __restrict__ x, const float* __restrict__ y,
          const float* __restrict__ W1, const float* __restrict__ W2,
          const float* __restrict__ W3, short* __restrict__ xb,
          short* __restrict__ yb, short* __restrict__ w1t,
          short* __restrict__ w23t) {
    const int b = blockIdx.x, tid = threadIdx.x;
    if (b < 2048) {
        const float* in = (b < 1024) ? x : y;
        short* o = (b < 1024) ? xb : yb;
        const int i = (b & 1023) * 256 + tid;
        const float4* p = (const float4*)in + (size_t)i * 2;
        float4 a = p[0], c4 = p[1];
        short8 s8;
        s8[0] = f2bf(a.x);  s8[1] = f2bf(a.y);
        s8[2] = f2bf(a.z);  s8[3] = f2bf(a.w);
        s8[4] = f2bf(c4.x); s8[5] = f2bf(c4.y);
        s8[6] = f2bf(c4.z); s8[7] = f2bf(c4.w);
        *((short8*)o + i) = s8;
        return;
    }
    __shared__ float t[32][33];
    const float* W; short* Wt; int b3;
    if (b < 3072) {
        const int b2 = b - 2048;                 // 0..1023
        const int z = b2 >> 9;                   // 0: W2, 1: W3
        W = z ? W3 : W2;
        Wt = w23t + (size_t)z * 1024 * 512;
        b3 = b2 & 511;
    } else {
        W = W1; Wt = w1t; b3 = b - 3072;         // 0..511
    }
    const int bx = (b3 & 31) * 32, by = (b3 >> 5) * 32;
    const int tx = tid & 31, ty = tid >> 5;
    #pragma unroll
    for (int j = 0; j < 4; ++j)
        t[ty + j * 8][tx] = W[(size_t)(by + ty + j * 8) * 1024 + bx + tx];
    __syncthreads();
    #pragma unroll
    for (int j = 0; j < 4; ++j)
        Wt[(size_t)(bx + ty + j * 8) * 512 + by + tx] = f2bf(t[tx][ty + j * 8]);
}

// --- generic MFMA tile: C[128x128] = A[.,K] * Bt[.,K]^T --------------------
// 4 waves 2x2; OUTMODE: 0 = f32 store, 1 = bf16 store, 2 = bf16*scale.
// BK=64, dbuf 2x32KB, 1 __syncthreads per step, XOR-swizzled LDS (T2).
// Buffer layout: [A 128 rows x 128B][B 128 rows x 128B]; LDS holds global
// chunk (row, c^(row&7)) at physical (row, c) -> read addr XORs the same.
template <int OUTMODE>
__device__ __forceinline__
void gemm_tile(const short* __restrict__ A, int lda,
               const short* __restrict__ Bt, int ldb,
               void* __restrict__ Cout, int ldc, int K,
               int bx, int by, float scale, char* smem) {
    const int tid = threadIdx.x;
    const int wave = tid >> 6, lane = tid & 63;
    const int quad = lane >> 4, ml = lane & 15;
    const int m0 = by * 128, n0 = bx * 128;
    const int wm0 = (wave >> 1) * 64, wn0 = (wave & 1) * 64;
    const int rl = lane >> 3;            // row within an 8-row group (0..7)
    const int ch = lane & 7;             // 16B chunk within 128B row (0..7)
    const int sch = ch ^ rl;             // source-swizzled chunk (involution)

    f32x4 acc[4][4];
    #pragma unroll
    for (int i = 0; i < 4; ++i)
        #pragma unroll
        for (int j = 0; j < 4; ++j) {
            acc[i][j][0] = 0.f; acc[i][j][1] = 0.f;
            acc[i][j][2] = 0.f; acc[i][j][3] = 0.f;
        }

    // Stage A[128x64] + B[128x64] bf16. 8 gl_lds per thread; each instr
    // covers 8 rows x 128B (full cache lines). r&7 == rl so global chunk
    // ch^rl lands at physical chunk ch -> read side XORs row&7.
    auto STAGE = [&](char* sbuf, int kt) {
        #pragma unroll
        for (int j = 0; j < 4; ++j) {
            const int r = (wave * 4 + j) * 8 + rl;
            gl_lds16(A + (size_t)(m0 + r) * lda + kt + sch * 8,
                     sbuf + (wave * 4 + j) * 1024 + lane * 16);
        }
        #pragma unroll
        for (int j = 0; j < 4; ++j) {
            const int r = (wave * 4 + j) * 8 + rl;
            gl_lds16(Bt + (size_t)(n0 + r) * ldb + kt + sch * 8,
                     sbuf + 16384 + (wave * 4 + j) * 1024 + lane * 16);
        }
    };

    const int nt = K >> 6;               // >= 4 at every call site
    STAGE(smem, 0);
    __syncthreads();                     // drain vmcnt(0): buf0 ready

    for (int t = 0; t < nt; ++t) {
        char* sbuf = smem + (t & 1) * 32768;
        if (t + 1 < nt)
            STAGE(smem + ((t + 1) & 1) * 32768, (t + 1) * 64);  // prefetch

        const short* sA = (const short*)sbuf;
        const short* sB = (const short*)(sbuf + 16384);
        #pragma unroll
        for (int kk = 0; kk < 2; ++kk) {
            short8 af[4], bfr[4];
            #pragma unroll
            for (int mt = 0; mt < 4; ++mt) {
                const int row = wm0 + mt * 16 + ml;
                af[mt] = *(const short8*)(sA + row * 64 +
                                          (((kk << 2) + quad) ^ (row & 7)) * 8);
            }
            #pragma unroll
            for (int nt2 = 0; nt2 < 4; ++nt2) {
                const int row = wn0 + nt2 * 16 + ml;
                bfr[nt2] = *(const short8*)(sB + row * 64 +
                                            (((kk << 2) + quad) ^ (row & 7)) * 8);
            }
            #pragma unroll
            for (int mt = 0; mt < 4; ++mt)
                #pragma unroll
                for (int nt2 = 0; nt2 < 4; ++nt2)
                    acc[mt][nt2] = __builtin_amdgcn_mfma_f32_16x16x32_bf16(
                        af[mt], bfr[nt2], acc[mt][nt2], 0, 0, 0);
        }
        __syncthreads();  // next buf ready; all waves done reading sbuf
    }

    // C/D layout: col = lane&15, row = quad*4 + reg
    #pragma unroll
    for (int mt = 0; mt < 4; ++mt)
        #pragma unroll
        for (int nt2 = 0; nt2 < 4; ++nt2) {
            const int col = n0 + wn0 + nt2 * 16 + ml;
            #pragma unroll
            for (int r = 0; r < 4; ++r) {
                const int row = m0 + wm0 + mt * 16 + quad * 4 + r;
                float v = acc[mt][nt2][r];
                if (OUTMODE == 2) v *= scale;
                if (OUTMODE == 0)
                    ((float*)Cout)[(size_t)row * ldc + col] = v;
                else
                    ((short*)Cout)[(size_t)row * ldc + col] = f2bf(v);
            }
        }
}

// stage_b: 768 blocks. After XCD swizzle: b<512 kvt tiles, else qb tiles.
// Bijective chunked swizzle for 768 = 8 XCDs x 96.
__global__ __launch_bounds__(256)
void stage_b(const short* __restrict__ yb, const short* __restrict__ w23t,
             const short* __restrict__ xb, const short* __restrict__ w1t,
             short* __restrict__ kvt, short* __restrict__ qb) {
    __shared__ char smem[65536];
    const int b = (blockIdx.x & 7) * 96 + (blockIdx.x >> 3);
    if (b < 512) {
        // kvt[2048,4096] = w23t @ yb^T : m-tiles 16, n-tiles 32
        gemm_tile<1>(w23t, 512, yb, 512, kvt, 4096, 512,
                     b & 31, b >> 5, 1.f, smem);
    } else {
        // qb[4096,1024] = xb @ w1t^T : m-tiles 32, n-tiles 8
        const int b2 = b - 512;
        gemm_tile<1>(xb, 512, w1t, 512, qb, 1024, 512,
                     b2 & 7, b2 >> 3, 1.f, smem);
    }
}

// build_u: grid (16,8); Ut tile (s,h) = scale * V_rows @ K_rows^T, K=256.
__global__ __launch_bounds__(256)
void build_u(const short* __restrict__ kvt, const float* __restrict__ cw,
             short* __restrict__ Ut) {
    __shared__ char smem[65536];
    const int s = blockIdx.x, h = blockIdx.y;
    const float scale = cw[h] * (0.08838834764831845f / 256.0f);
    gemm_tile<2>(kvt + (size_t)(1024 + h * 128) * 4096 + s * 256, 4096,  // V
                 kvt + (size_t)(h * 128) * 4096 + s * 256, 4096,         // K
                 Ut + (size_t)(s * 128) * 1024 + h * 128, 1024, 256,
                 0, 0, scale, smem);
}

// out[4096,2048] = qb @ Ut^T, fp32, K=1024. 512 blocks (XCD-swizzled).
__global__ __launch_bounds__(256)
void gemm_out(const short* __restrict__ qb, const short* __restrict__ Ut,
              float* __restrict__ out) {
    __shared__ char smem[65536];
    const int b = (blockIdx.x & 7) * 64 + (blockIdx.x >> 3);
    gemm_tile<0>(qb, 1024, Ut, 1024, out, 2048, 1024,
                 b & 15, b >> 4, 1.f, smem);
}

extern "C" void kernel_launch(void* const* d_in, const int* in_sizes, int n_in,
                              void* d_out, int out_size, void* d_ws, size_t ws_size,
                              hipStream_t stream) {
    const float* x  = (const float*)d_in[0];  // [4096, 512]
    const float* y  = (const float*)d_in[1];  // [4096, 512]
    const float* W1 = (const float*)d_in[2];  // [512, 1024]
    const float* W2 = (const float*)d_in[3];
    const float* W3 = (const float*)d_in[4];
    const float* cw = (const float*)d_in[5];  // [8]
    float* out = (float*)d_out;               // [4096, 16, 128]

    short* xb   = (short*)d_ws;                       // 4096*512
    short* yb   = xb   + (size_t)4096 * 512;          // 4096*512
    short* w1t  = yb   + (size_t)4096 * 512;          // 1024*512 (transposed)
    short* w23t = w1t  + (size_t)1024 * 512;          // 2048*512 (transposed)
    short* kvt  = w23t + (size_t)2048 * 512;          // 2048*4096
    short* qb   = kvt  + (size_t)2048 * 4096;         // 4096*1024
    short* Ut   = qb   + (size_t)4096 * 1024;         // 2048*1024

    prep<<<3584, 256, 0, stream>>>(x, y, W1, W2, W3, xb, yb, w1t, w23t);
    stage_b<<<768, 256, 0, stream>>>(yb, w23t, xb, w1t, kvt, qb);
    build_u<<<dim3(16, 8), 256, 0, stream>>>(kvt, cw, Ut);
    gemm_out<<<512, 256, 0, stream>>>(qb, Ut, out);
}